// Round 1
// baseline (198.506 us; speedup 1.0000x reference)
//
#include <hip/hip_runtime.h>

constexpr int N_PTS = 16384;
constexpr int KN = 16;   // neighbors
constexpr int P  = 15;   // kernel points
constexpr int CI = 64;
constexpr int CO = 128;
constexpr int TQ = 8;    // query points per block

__global__ __launch_bounds__(256) void kpconv_kernel(
    const float* __restrict__ query,    // [N][3]
    const float* __restrict__ support,  // [M][3]
    const int*   __restrict__ nidx,     // [N][KN]
    const float* __restrict__ feats,    // [M][CI]
    const float* __restrict__ W,        // [P][CI][CO]
    const float* __restrict__ kp,       // [P][3]
    float* __restrict__ out)            // [N][CO]
{
    __shared__ float sKp[P][3];
    __shared__ int   sIdx[TQ][KN];
    __shared__ __align__(16) float sInfl[TQ][KN][16];  // p padded to 16
    __shared__ __align__(16) float sAgg[TQ][P][CI];    // 30720 B

    const int t  = threadIdx.x;
    const int n0 = blockIdx.x * TQ;

    // stage kernel points
    if (t < P * 3) ((float*)sKp)[t] = kp[t];
    __syncthreads();

    // ---- Phase A: influences, one thread per (pt, k) ----
    if (t < TQ * KN) {
        const int pt = t >> 4, k = t & (KN - 1);
        const int n = n0 + pt;
        const int idx = nidx[n * KN + k];
        sIdx[pt][k] = idx;
        const float rx = support[idx * 3 + 0] - query[n * 3 + 0];
        const float ry = support[idx * 3 + 1] - query[n * 3 + 1];
        const float rz = support[idx * 3 + 2] - query[n * 3 + 2];
        #pragma unroll
        for (int p = 0; p < P; ++p) {
            const float dx = rx - sKp[p][0];
            const float dy = ry - sKp[p][1];
            const float dz = rz - sKp[p][2];
            const float d = sqrtf(dx * dx + dy * dy + dz * dz);
            sInfl[pt][k][p] = fmaxf(1.0f - d, 0.0f);
        }
        sInfl[pt][k][15] = 0.0f;
    }
    __syncthreads();

    // ---- Phase B: agg[pt][p][c] = sum_k infl[pt][k][p] * feat[idx][c] ----
    // 512 (pt,c) pairs over 2 iterations; a wave has uniform pt -> LDS broadcast.
    #pragma unroll
    for (int it = 0; it < 2; ++it) {
        const int pair = t + it * 256;
        const int pt = pair >> 6;
        const int c  = pair & (CI - 1);
        float acc[P];
        #pragma unroll
        for (int p = 0; p < P; ++p) acc[p] = 0.0f;
        #pragma unroll
        for (int k = 0; k < KN; ++k) {
            const float f = feats[(size_t)sIdx[pt][k] * CI + c];  // coalesced row
            const float4* ip = (const float4*)sInfl[pt][k];
            const float4 i0 = ip[0], i1 = ip[1], i2 = ip[2], i3 = ip[3];
            acc[0]  = fmaf(i0.x, f, acc[0]);
            acc[1]  = fmaf(i0.y, f, acc[1]);
            acc[2]  = fmaf(i0.z, f, acc[2]);
            acc[3]  = fmaf(i0.w, f, acc[3]);
            acc[4]  = fmaf(i1.x, f, acc[4]);
            acc[5]  = fmaf(i1.y, f, acc[5]);
            acc[6]  = fmaf(i1.z, f, acc[6]);
            acc[7]  = fmaf(i1.w, f, acc[7]);
            acc[8]  = fmaf(i2.x, f, acc[8]);
            acc[9]  = fmaf(i2.y, f, acc[9]);
            acc[10] = fmaf(i2.z, f, acc[10]);
            acc[11] = fmaf(i2.w, f, acc[11]);
            acc[12] = fmaf(i3.x, f, acc[12]);
            acc[13] = fmaf(i3.y, f, acc[13]);
            acc[14] = fmaf(i3.z, f, acc[14]);
        }
        #pragma unroll
        for (int p = 0; p < P; ++p) sAgg[pt][p][c] = acc[p];
    }
    __syncthreads();

    // ---- Phase C: out[n0+pt][o] = sum_{p,c} agg[pt][p][c] * W[p][c][o] ----
    // thread: o = t&127, ph = t>>7 owns pts ph*4..ph*4+3.
    const int o  = t & (CO - 1);
    const int ph = t >> 7;
    float acc[4] = {0.f, 0.f, 0.f, 0.f};
    for (int p = 0; p < P; ++p) {
        #pragma unroll
        for (int c4 = 0; c4 < CI / 4; ++c4) {
            const int c = c4 * 4;
            const float w0 = W[(size_t)(p * CI + c + 0) * CO + o];
            const float w1 = W[(size_t)(p * CI + c + 1) * CO + o];
            const float w2 = W[(size_t)(p * CI + c + 2) * CO + o];
            const float w3 = W[(size_t)(p * CI + c + 3) * CO + o];
            #pragma unroll
            for (int i = 0; i < 4; ++i) {
                const float4 a = *(const float4*)&sAgg[ph * 4 + i][p][c];  // broadcast
                acc[i] = fmaf(a.x, w0, acc[i]);
                acc[i] = fmaf(a.y, w1, acc[i]);
                acc[i] = fmaf(a.z, w2, acc[i]);
                acc[i] = fmaf(a.w, w3, acc[i]);
            }
        }
    }
    #pragma unroll
    for (int i = 0; i < 4; ++i) {
        out[(size_t)(n0 + ph * 4 + i) * CO + o] = acc[i];
    }
}

extern "C" void kernel_launch(void* const* d_in, const int* in_sizes, int n_in,
                              void* d_out, int out_size, void* d_ws, size_t ws_size,
                              hipStream_t stream) {
    const float* query   = (const float*)d_in[0];
    const float* support = (const float*)d_in[1];
    const int*   nidx    = (const int*)d_in[2];
    const float* feats   = (const float*)d_in[3];
    const float* W       = (const float*)d_in[4];
    const float* kp      = (const float*)d_in[5];
    float* out = (float*)d_out;

    dim3 grid(N_PTS / TQ);
    dim3 block(256);
    hipLaunchKernelGGL(kpconv_kernel, grid, block, 0, stream,
                       query, support, nidx, feats, W, kp, out);
}

// Round 3
// 97.103 us; speedup vs baseline: 2.0443x; 2.0443x over previous
//
#include <hip/hip_runtime.h>

typedef __attribute__((ext_vector_type(8))) short bf16x8;
typedef __attribute__((ext_vector_type(4))) float f32x4;

constexpr int N_PTS = 16384;
constexpr int KN = 16;    // neighbors
constexpr int P  = 15;    // kernel points
constexpr int CI = 64;
constexpr int CO = 128;
constexpr int QB = 16;    // query points per block
constexpr int KTOT   = P * CI;     // 960
constexpr int KSTEPS = KTOT / 32;  // 30
constexpr int NTILES = CO / 16;    // 8
constexpr int AGG_PITCH = KTOT + 8; // 968 bf16/row -> bank-conflict-free frag reads

static __device__ __forceinline__ unsigned short f2bf(float f) {
    unsigned u = __float_as_uint(f);
    u = (u + 0x7fffu + ((u >> 16) & 1u)) >> 16;  // RNE
    return (unsigned short)u;
}

// ---- Prep: W (fp32 [P][CI][CO]) -> bf16 B-fragments WB[kstep][ntile][lane][8]
__global__ __launch_bounds__(256) void prep_w(const float* __restrict__ W,
                                              unsigned short* __restrict__ WB) {
    const int t = blockIdx.x * 256 + threadIdx.x;   // 30*8*64 = 15360 total
    const int s  = t >> 9;          // kstep
    const int nt = (t >> 6) & 7;    // ntile
    const int l  = t & 63;          // lane
    const int kb = s * 32 + ((l >> 4) * 8);
    const int o  = nt * 16 + (l & 15);
    unsigned short v[8];
    #pragma unroll
    for (int j = 0; j < 8; ++j) {
        v[j] = f2bf(W[(size_t)(kb + j) * CO + o]);
    }
    uint4 q;
    q.x = v[0] | ((unsigned)v[1] << 16);
    q.y = v[2] | ((unsigned)v[3] << 16);
    q.z = v[4] | ((unsigned)v[5] << 16);
    q.w = v[6] | ((unsigned)v[7] << 16);
    *(uint4*)&WB[(size_t)t * 8] = q;
}

__global__ __launch_bounds__(256) void kpconv_main(
    const float* __restrict__ query,    // [N][3]
    const float* __restrict__ support,  // [M][3]
    const int*   __restrict__ nidx,     // [N][KN]
    const float* __restrict__ feats,    // [M][CI]
    const unsigned short* __restrict__ WB, // bf16 fragments
    const float* __restrict__ kp,       // [P][3]
    float* __restrict__ out)            // [N][CO]
{
    __shared__ float sKp[P][3];
    __shared__ int   sIdx[QB][KN];
    __shared__ __align__(16) float sInfl[QB][KN][16];          // 16 KB
    __shared__ __align__(16) unsigned short sAgg[QB][AGG_PITCH]; // ~30.3 KB

    const int t  = threadIdx.x;
    const int n0 = blockIdx.x * QB;

    if (t < P * 3) ((float*)sKp)[t] = kp[t];
    __syncthreads();

    // ---- Phase A: one thread per (pt, k) ----
    {
        const int pt = t >> 4, k = t & 15;
        const int n = n0 + pt;
        const int idx = nidx[n * KN + k];
        sIdx[pt][k] = idx;
        const float rx = support[idx * 3 + 0] - query[n * 3 + 0];
        const float ry = support[idx * 3 + 1] - query[n * 3 + 1];
        const float rz = support[idx * 3 + 2] - query[n * 3 + 2];
        #pragma unroll
        for (int p = 0; p < P; ++p) {
            const float dx = rx - sKp[p][0];
            const float dy = ry - sKp[p][1];
            const float dz = rz - sKp[p][2];
            sInfl[pt][k][p] = fmaxf(1.0f - sqrtf(dx*dx + dy*dy + dz*dz), 0.0f);
        }
        sInfl[pt][k][15] = 0.0f;
    }
    __syncthreads();

    // ---- Phase B: thread (pt = t>>4, c = (t&15)*4); agg[pt][p][c..c+3] ----
    {
        const int pt = t >> 4;
        const int c  = (t & 15) * 4;
        int idxv[KN];
        {
            const int4* ip = (const int4*)sIdx[pt];
            #pragma unroll
            for (int k4 = 0; k4 < 4; ++k4) {
                const int4 v = ip[k4];
                idxv[k4*4+0] = v.x; idxv[k4*4+1] = v.y;
                idxv[k4*4+2] = v.z; idxv[k4*4+3] = v.w;
            }
        }
        float acc[P][4];
        #pragma unroll
        for (int p = 0; p < P; ++p)
            #pragma unroll
            for (int j = 0; j < 4; ++j) acc[p][j] = 0.0f;

        #pragma unroll
        for (int k = 0; k < KN; ++k) {
            const float4 f = *(const float4*)&feats[(size_t)idxv[k] * CI + c];
            float iv[16];
            {
                const float4* ip = (const float4*)sInfl[pt][k];  // broadcast reads
                *(float4*)&iv[0]  = ip[0];
                *(float4*)&iv[4]  = ip[1];
                *(float4*)&iv[8]  = ip[2];
                *(float4*)&iv[12] = ip[3];
            }
            #pragma unroll
            for (int p = 0; p < P; ++p) {
                acc[p][0] = fmaf(iv[p], f.x, acc[p][0]);
                acc[p][1] = fmaf(iv[p], f.y, acc[p][1]);
                acc[p][2] = fmaf(iv[p], f.z, acc[p][2]);
                acc[p][3] = fmaf(iv[p], f.w, acc[p][3]);
            }
        }
        #pragma unroll
        for (int p = 0; p < P; ++p) {
            uint2 w;
            w.x = f2bf(acc[p][0]) | ((unsigned)f2bf(acc[p][1]) << 16);
            w.y = f2bf(acc[p][2]) | ((unsigned)f2bf(acc[p][3]) << 16);
            *(uint2*)&sAgg[pt][p * CI + c] = w;
        }
    }
    __syncthreads();

    // ---- Phase C: wave w handles ntiles 2w, 2w+1; K-loop over 30 steps ----
    {
        const int w = t >> 6, l = t & 63;
        const int row = l & 15;
        const int kq  = (l >> 4) * 8;
        f32x4 c0 = {0.f, 0.f, 0.f, 0.f};
        f32x4 c1 = {0.f, 0.f, 0.f, 0.f};
        const unsigned short* aggRow = &sAgg[row][kq];
        const unsigned short* wb0 = &WB[(size_t)((0 * NTILES + 2 * w) * 64 + l) * 8];
        #pragma unroll 2
        for (int s = 0; s < KSTEPS; ++s) {
            const bf16x8 a  = *(const bf16x8*)&aggRow[s * 32];
            const bf16x8 b0 = *(const bf16x8*)&wb0[(size_t)(s * NTILES) * 64 * 8];
            const bf16x8 b1 = *(const bf16x8*)&wb0[(size_t)(s * NTILES + 1) * 64 * 8];
            c0 = __builtin_amdgcn_mfma_f32_16x16x32_bf16(a, b0, c0, 0, 0, 0);
            c1 = __builtin_amdgcn_mfma_f32_16x16x32_bf16(a, b1, c1, 0, 0, 0);
        }
        const int rbase = (l >> 4) * 4;
        const int o0 = (2 * w) * 16 + (l & 15);
        #pragma unroll
        for (int r = 0; r < 4; ++r) {
            const int pt = rbase + r;
            out[(size_t)(n0 + pt) * CO + o0]      = c0[r];
            out[(size_t)(n0 + pt) * CO + o0 + 16] = c1[r];
        }
    }
}

extern "C" void kernel_launch(void* const* d_in, const int* in_sizes, int n_in,
                              void* d_out, int out_size, void* d_ws, size_t ws_size,
                              hipStream_t stream) {
    const float* query   = (const float*)d_in[0];
    const float* support = (const float*)d_in[1];
    const int*   nidx    = (const int*)d_in[2];
    const float* feats   = (const float*)d_in[3];
    const float* W       = (const float*)d_in[4];
    const float* kp      = (const float*)d_in[5];
    float* out = (float*)d_out;
    unsigned short* WB = (unsigned short*)d_ws;   // 245760 B needed

    hipLaunchKernelGGL(prep_w, dim3(KSTEPS * NTILES * 64 / 256), dim3(256), 0, stream, W, WB);
    hipLaunchKernelGGL(kpconv_main, dim3(N_PTS / QB), dim3(256), 0, stream,
                       query, support, nidx, feats, WB, kp, out);
}